// Round 1
// baseline (299.671 us; speedup 1.0000x reference)
//
#include <hip/hip_runtime.h>
#include <math.h>

// ---- problem constants ----
#define B_N    2
#define S_LEN  2048
#define DMODEL 192
#define HQ_N   8
#define HKV_N  4
#define DH_N   24
#define KAUG   160   // 24 q/k + 64 cos + 64 sin + 8 zero pad (= 5 * 32)

typedef __attribute__((ext_vector_type(8))) short bf16x8;
typedef __attribute__((ext_vector_type(4))) float f32x4;

static __device__ __forceinline__ unsigned short f2bf(float f) {
    union { float f; unsigned u; } v; v.f = f;
    unsigned r = v.u + 0x7FFFu + ((v.u >> 16) & 1u);
    return (unsigned short)(r >> 16);
}

// ============================================================
// K1: projections + phase tables -> QA (bf16, pre-scaled), KA (bf16), VT (bf16, transposed)
// QA[b][h][s][160]  = [alpha*SCALE*q(24) | (beta/64)*cos(64) | (beta/64)*sin(64) | 0(8)]
// KA[b][kvh][s][160]= [k(24)             | cos(64)           | sin(64)           | 0(8)]
// VT[b][kvh][32][S] = v transposed (d-major), rows 24..31 zero
// ============================================================
__global__ __launch_bounds__(256) void prep_kernel(
    const float* __restrict__ x, const float* __restrict__ Wq,
    const float* __restrict__ Wkv, const float* __restrict__ alpha_p,
    const float* __restrict__ beta_p,
    unsigned short* __restrict__ QA, unsigned short* __restrict__ KA,
    unsigned short* __restrict__ VT)
{
    __shared__ __align__(16) float xs[16][196];   // stride 196 breaks bank aliasing
    const int tid = threadIdx.x;
    const int row0 = blockIdx.x * 16;             // global row in [0, B*S)

    // stage 16 rows of x (16*192 floats)
    #pragma unroll
    for (int c = 0; c < 12; ++c) {
        int idx = c * 256 + tid;
        int r = idx / 192, col = idx % 192;
        xs[r][col] = x[(size_t)(row0 + r) * 192 + col];
    }
    __syncthreads();

    const float alpha = alpha_p[0], beta = beta_p[0];
    const float qscale = alpha * (1.0f / sqrtf(24.0f));
    const float bf = beta / 64.0f;

    const int ty = tid >> 4, tx = tid & 15;
    const int grow = row0 + ty;
    const int b = grow >> 11, s = grow & (S_LEN - 1);

    // 24 dot products per thread: cols c = tx + 16j; j<12 -> Wq row c, j>=12 -> Wkv row c-192
    float acc[24];
    #pragma unroll
    for (int j = 0; j < 24; ++j) acc[j] = 0.f;

    const float4* wq4  = (const float4*)(Wq  + (size_t)tx * 192);
    const float4* wkv4 = (const float4*)(Wkv + (size_t)tx * 192);

    for (int ch = 0; ch < 6; ++ch) {          // 6 chunks of 32 floats
        float4 xr[8];
        #pragma unroll
        for (int u = 0; u < 8; ++u) xr[u] = *(const float4*)&xs[ty][ch * 32 + u * 4];
        #pragma unroll
        for (int j = 0; j < 12; ++j) {
            const float4* wp  = wq4  + (size_t)j * (16 * 48) + ch * 8;
            const float4* wp2 = wkv4 + (size_t)j * (16 * 48) + ch * 8;
            #pragma unroll
            for (int u = 0; u < 8; ++u) {
                float4 wv = wp[u];
                acc[j] += xr[u].x * wv.x + xr[u].y * wv.y + xr[u].z * wv.z + xr[u].w * wv.w;
            }
            #pragma unroll
            for (int u = 0; u < 8; ++u) {
                float4 wv = wp2[u];
                acc[12 + j] += xr[u].x * wv.x + xr[u].y * wv.y + xr[u].z * wv.z + xr[u].w * wv.w;
            }
        }
    }

    #pragma unroll
    for (int j = 0; j < 24; ++j) {
        float a = acc[j];
        int c = tx + 16 * j;
        if (j < 12) {                       // q
            int h = c / 24, d = c % 24;
            QA[((size_t)(b * 8 + h) * S_LEN + s) * KAUG + d] = f2bf(a * qscale);
        } else if (j < 18) {                // k  (rows 0..95 of Wkv output)
            int cc = c - 192; int kvh = cc / 24, d = cc % 24;
            KA[((size_t)(b * 4 + kvh) * S_LEN + s) * KAUG + d] = f2bf(a);
        } else {                            // v  (rows 96..191)
            int cc = c - 288; int kvh = cc / 24, d = cc % 24;
            VT[((size_t)(b * 4 + kvh) * 32 + d) * S_LEN + s] = f2bf(a);
        }
    }

    // phases: n = tx + 16m
    #pragma unroll
    for (int m = 0; m < 4; ++m) {
        int n = tx + 16 * m;
        float ph = xs[ty][128 + n];
        float sp, cp;
        sincosf(ph, &sp, &cp);
        unsigned short cpa = f2bf(cp * bf), spa = f2bf(sp * bf);
        unsigned short cpk = f2bf(cp),      spk = f2bf(sp);
        #pragma unroll
        for (int h = 0; h < 8; ++h) {
            size_t base = ((size_t)(b * 8 + h) * S_LEN + s) * KAUG;
            QA[base + 24 + n] = cpa;
            QA[base + 88 + n] = spa;
        }
        #pragma unroll
        for (int kvh = 0; kvh < 4; ++kvh) {
            size_t base = ((size_t)(b * 4 + kvh) * S_LEN + s) * KAUG;
            KA[base + 24 + n] = cpk;
            KA[base + 88 + n] = spk;
        }
    }

    // zero pads: QA/KA dims 152..159, VT d-rows 24..31
    if (tx < 8) {
        #pragma unroll
        for (int h = 0; h < 8; ++h)
            QA[((size_t)(b * 8 + h) * S_LEN + s) * KAUG + 152 + tx] = 0;
        #pragma unroll
        for (int kvh = 0; kvh < 4; ++kvh)
            KA[((size_t)(b * 4 + kvh) * S_LEN + s) * KAUG + 152 + tx] = 0;
        #pragma unroll
        for (int kvh = 0; kvh < 4; ++kvh)
            VT[((size_t)(b * 4 + kvh) * 32 + 24 + tx) * S_LEN + s] = 0;
    }
}

// ============================================================
// K2: fused flash attention.  Grid = B*HQ*(S/64) blocks, 4 waves/block,
// wave w owns q rows [qb+16w, qb+16w+16).  Key tiles of 32.
// mfma_f32_16x16x32_bf16 layouts (m89-verified):
//   A: lane l holds A[l&15][(l>>4)*8+j]   B: lane l holds B[(l>>4)*8+j][l&15]
//   D: lane l reg r holds D[(l>>4)*4+r][l&15]
// ============================================================
__global__ __launch_bounds__(256) void attn_kernel(
    const unsigned short* __restrict__ QA, const unsigned short* __restrict__ KA,
    const unsigned short* __restrict__ VT, float* __restrict__ O)
{
    __shared__ __align__(16) unsigned short ka_lds[32][168]; // stride 336B (pad: 2-way banks)
    __shared__ __align__(16) unsigned short vt_lds[32][40];  // stride 80B
    __shared__ __align__(16) unsigned short pt_lds[4][32][20]; // per-wave P^T, stride 40B

    const int tid = threadIdx.x;
    const int wid = tid >> 6, lane = tid & 63;
    const int g = lane >> 4, lr = lane & 15;

    const int bid = blockIdx.x;
    const int t = (S_LEN / 64 - 1) - (bid >> 4);   // largest-first for load balance
    const int bh = bid & 15;
    const int b = bh >> 3, h = bh & 7;
    const int kvh = h >> 1;
    const int qb = t * 64;
    const int q0w = qb + wid * 16;

    const unsigned short* qa_base = QA + (size_t)(b * 8 + h) * S_LEN * KAUG;
    const unsigned short* ka_base = KA + (size_t)(b * 4 + kvh) * S_LEN * KAUG;
    const unsigned short* vt_base = VT + (size_t)(b * 4 + kvh) * 32 * S_LEN;

    // Q fragments: 5 K-chunks of 32
    bf16x8 qfrag[5];
    #pragma unroll
    for (int kc = 0; kc < 5; ++kc) {
        const unsigned short* p = qa_base + (size_t)(q0w + lr) * KAUG + kc * 32 + g * 8;
        qfrag[kc] = *(const bf16x8*)p;
    }

    f32x4 acc0 = {0.f, 0.f, 0.f, 0.f};
    f32x4 acc1 = {0.f, 0.f, 0.f, 0.f};
    float mrow[4] = {-1e30f, -1e30f, -1e30f, -1e30f};
    float lrow[4] = {0.f, 0.f, 0.f, 0.f};
    const int wave_qmax = q0w + 15;
    const int ntiles = 2 * t + 2;

    for (int kt = 0; kt < ntiles; ++kt) {
        const int n0 = kt * 32;
        __syncthreads();
        // stage KA tile: 32 rows x 80 dwords
        {
            const unsigned* src = (const unsigned*)ka_base + (size_t)n0 * 80;
            unsigned* dst = (unsigned*)&ka_lds[0][0];
            #pragma unroll
            for (int c = 0; c < 10; ++c) {
                int idx = c * 256 + tid;
                int r = idx / 80, col = idx % 80;
                dst[r * 84 + col] = src[(size_t)r * 80 + col];
            }
            // stage VT tile: 32 d-rows x 16 dwords (32 keys)
            const unsigned* vsrc = (const unsigned*)vt_base + (n0 >> 1);
            unsigned* vdst = (unsigned*)&vt_lds[0][0];
            #pragma unroll
            for (int c = 0; c < 2; ++c) {
                int idx = c * 256 + tid;
                int r = idx / 16, col = idx % 16;
                vdst[r * 20 + col] = vsrc[(size_t)r * 1024 + col];
            }
        }
        __syncthreads();
        if (n0 > wave_qmax) continue;   // fully masked for this wave

        // ---- scores: 2 key-col tiles x 5 K-chunks ----
        f32x4 sf[2] = {{0.f,0.f,0.f,0.f},{0.f,0.f,0.f,0.f}};
        #pragma unroll
        for (int nc = 0; nc < 2; ++nc) {
            #pragma unroll
            for (int kc = 0; kc < 5; ++kc) {
                bf16x8 bfr = *(const bf16x8*)&ka_lds[nc * 16 + lr][kc * 32 + g * 8];
                sf[nc] = __builtin_amdgcn_mfma_f32_16x16x32_bf16(qfrag[kc], bfr, sf[nc], 0, 0, 0);
            }
        }
        // ---- causal mask ----
        #pragma unroll
        for (int nc = 0; nc < 2; ++nc) {
            int n = n0 + nc * 16 + lr;
            #pragma unroll
            for (int r = 0; r < 4; ++r) {
                int q = q0w + g * 4 + r;
                if (n > q) sf[nc][r] = -1e30f;
            }
        }
        // ---- online softmax (row = across 16 lanes of the group) ----
        float tmax[4];
        #pragma unroll
        for (int r = 0; r < 4; ++r) tmax[r] = fmaxf(sf[0][r], sf[1][r]);
        #pragma unroll
        for (int off = 1; off < 16; off <<= 1) {
            #pragma unroll
            for (int r = 0; r < 4; ++r) tmax[r] = fmaxf(tmax[r], __shfl_xor(tmax[r], off, 64));
        }
        float corr[4];
        #pragma unroll
        for (int r = 0; r < 4; ++r) {
            float mnew = fmaxf(mrow[r], tmax[r]);
            corr[r] = __expf(mrow[r] - mnew);
            mrow[r] = mnew;
        }
        float p0[4], p1[4], tsum[4];
        #pragma unroll
        for (int r = 0; r < 4; ++r) {
            p0[r] = __expf(sf[0][r] - mrow[r]);
            p1[r] = __expf(sf[1][r] - mrow[r]);
            tsum[r] = p0[r] + p1[r];
        }
        #pragma unroll
        for (int off = 1; off < 16; off <<= 1) {
            #pragma unroll
            for (int r = 0; r < 4; ++r) tsum[r] += __shfl_xor(tsum[r], off, 64);
        }
        #pragma unroll
        for (int r = 0; r < 4; ++r) {
            lrow[r] = lrow[r] * corr[r] + tsum[r];
            acc0[r] *= corr[r];
            acc1[r] *= corr[r];
        }
        // ---- P^T to per-wave LDS:  pt[key][q], lane writes 4 q's (8B) ----
        {
            ushort4 pk;
            pk.x = f2bf(p0[0]); pk.y = f2bf(p0[1]); pk.z = f2bf(p0[2]); pk.w = f2bf(p0[3]);
            *(ushort4*)&pt_lds[wid][lr][g * 4] = pk;
            pk.x = f2bf(p1[0]); pk.y = f2bf(p1[1]); pk.z = f2bf(p1[2]); pk.w = f2bf(p1[3]);
            *(ushort4*)&pt_lds[wid][16 + lr][g * 4] = pk;
        }
        // ---- PV: A = P (gather from per-wave P^T), B = V (contiguous from VT) ----
        bf16x8 afr;
        #pragma unroll
        for (int j = 0; j < 8; ++j) afr[j] = (short)pt_lds[wid][g * 8 + j][lr];
        {
            bf16x8 bfr0 = *(const bf16x8*)&vt_lds[lr][g * 8];
            acc0 = __builtin_amdgcn_mfma_f32_16x16x32_bf16(afr, bfr0, acc0, 0, 0, 0);
            bf16x8 bfr1 = *(const bf16x8*)&vt_lds[16 + lr][g * 8];
            acc1 = __builtin_amdgcn_mfma_f32_16x16x32_bf16(afr, bfr1, acc1, 0, 0, 0);
        }
    }

    // ---- finalize: O[b][q][h*24+d] = acc/l ----
    float inv[4];
    #pragma unroll
    for (int r = 0; r < 4; ++r) inv[r] = 1.0f / lrow[r];
    {
        int d = lr;                 // acc0: d 0..15
        #pragma unroll
        for (int r = 0; r < 4; ++r) {
            int q = q0w + g * 4 + r;
            O[((size_t)b * S_LEN + q) * DMODEL + h * 24 + d] = acc0[r] * inv[r];
        }
        d = 16 + lr;                // acc1: d 16..31, keep d<24
        if (d < 24) {
            #pragma unroll
            for (int r = 0; r < 4; ++r) {
                int q = q0w + g * 4 + r;
                O[((size_t)b * S_LEN + q) * DMODEL + h * 24 + d] = acc1[r] * inv[r];
            }
        }
    }
}

// ============================================================
// K3: out = O @ Wo^T  (fp32)
// ============================================================
__global__ __launch_bounds__(256) void proj_kernel(
    const float* __restrict__ O, const float* __restrict__ Wo,
    float* __restrict__ out)
{
    __shared__ __align__(16) float os[16][196];
    const int tid = threadIdx.x;
    const int row0 = blockIdx.x * 16;
    #pragma unroll
    for (int c = 0; c < 12; ++c) {
        int idx = c * 256 + tid;
        int r = idx / 192, col = idx % 192;
        os[r][col] = O[(size_t)(row0 + r) * 192 + col];
    }
    __syncthreads();
    const int ty = tid >> 4, tx = tid & 15;
    float acc[12];
    #pragma unroll
    for (int j = 0; j < 12; ++j) acc[j] = 0.f;
    const float4* wo4 = (const float4*)(Wo + (size_t)tx * 192);
    for (int ch = 0; ch < 6; ++ch) {
        float4 xr[8];
        #pragma unroll
        for (int u = 0; u < 8; ++u) xr[u] = *(const float4*)&os[ty][ch * 32 + u * 4];
        #pragma unroll
        for (int j = 0; j < 12; ++j) {
            const float4* wp = wo4 + (size_t)j * (16 * 48) + ch * 8;
            #pragma unroll
            for (int u = 0; u < 8; ++u) {
                float4 wv = wp[u];
                acc[j] += xr[u].x * wv.x + xr[u].y * wv.y + xr[u].z * wv.z + xr[u].w * wv.w;
            }
        }
    }
    #pragma unroll
    for (int j = 0; j < 12; ++j)
        out[(size_t)(row0 + ty) * 192 + tx + 16 * j] = acc[j];
}

// ============================================================
extern "C" void kernel_launch(void* const* d_in, const int* in_sizes, int n_in,
                              void* d_out, int out_size, void* d_ws, size_t ws_size,
                              hipStream_t stream) {
    const float* x     = (const float*)d_in[0];
    const float* Wq    = (const float*)d_in[1];
    const float* Wkv   = (const float*)d_in[2];
    const float* Wo    = (const float*)d_in[3];
    const float* alpha = (const float*)d_in[4];
    const float* beta  = (const float*)d_in[5];

    char* ws = (char*)d_ws;
    const size_t QA_BYTES = (size_t)B_N * 8 * S_LEN * KAUG * 2;   // 10,485,760
    const size_t KA_BYTES = (size_t)B_N * 4 * S_LEN * KAUG * 2;   //  5,242,880
    const size_t VT_BYTES = (size_t)B_N * 4 * 32 * S_LEN * 2;     //  1,048,576
    unsigned short* QA = (unsigned short*)ws;
    unsigned short* KA = (unsigned short*)(ws + QA_BYTES);
    unsigned short* VT = (unsigned short*)(ws + QA_BYTES + KA_BYTES);
    float* O           = (float*)(ws + QA_BYTES + KA_BYTES + VT_BYTES);
    float* out = (float*)d_out;

    hipLaunchKernelGGL(prep_kernel, dim3((B_N * S_LEN) / 16), dim3(256), 0, stream,
                       x, Wq, Wkv, alpha, beta, QA, KA, VT);
    hipLaunchKernelGGL(attn_kernel, dim3(B_N * HQ_N * (S_LEN / 64)), dim3(256), 0, stream,
                       QA, KA, VT, O);
    hipLaunchKernelGGL(proj_kernel, dim3((B_N * S_LEN) / 16), dim3(256), 0, stream,
                       O, Wo, out);
}

// Round 2
// 119.956 us; speedup vs baseline: 2.4982x; 2.4982x over previous
//
#include <hip/hip_runtime.h>
#include <math.h>

// ---- problem constants ----
#define B_N    2
#define S_LEN  2048
#define DMODEL 192
#define HQ_N   8
#define HKV_N  4
#define DH_N   24
#define KAUG   160   // 24 q/k + 64 cos + 64 sin + 8 zero pad (= 5 * 32)

typedef __attribute__((ext_vector_type(8))) short bf16x8;
typedef __attribute__((ext_vector_type(4))) float f32x4;

static __device__ __forceinline__ unsigned short f2bf(float f) {
    union { float f; unsigned u; } v; v.f = f;
    unsigned r = v.u + 0x7FFFu + ((v.u >> 16) & 1u);
    return (unsigned short)(r >> 16);
}

// ============================================================
// K0: convert — x->bf16, W->bf16, phase sincos -> QA/KA phase+pad
// sections, VT pad rows.  Blocks:
//   [0,1024)      : 4 x-rows per block (wave per row)
//   [1024,1038)   : W conversion (Wq|Wkv|Wo -> Wb[576][192] bf16)
//   [1038,1046)   : VT pad rows 24..31 zero
// ============================================================
__global__ __launch_bounds__(256) void convert_kernel(
    const float* __restrict__ x, const float* __restrict__ Wq,
    const float* __restrict__ Wkv, const float* __restrict__ Wo,
    const float* __restrict__ beta_p,
    unsigned short* __restrict__ xb, unsigned short* __restrict__ Wb,
    unsigned short* __restrict__ QA, unsigned short* __restrict__ KA,
    unsigned short* __restrict__ VT)
{
    const int blk = blockIdx.x, tid = threadIdx.x;
    if (blk < 1024) {
        const int wid = tid >> 6, lane = tid & 63;
        const int row = blk * 4 + wid;
        const int b = row >> 11, s = row & (S_LEN - 1);
        const float* xr = x + (size_t)row * DMODEL;
        // x -> bf16 (48 lanes x float4)
        if (lane < 48) {
            float4 v = ((const float4*)xr)[lane];
            uint2 w;
            w.x = (unsigned)f2bf(v.x) | ((unsigned)f2bf(v.y) << 16);
            w.y = (unsigned)f2bf(v.z) | ((unsigned)f2bf(v.w) << 16);
            *(uint2*)(xb + (size_t)row * DMODEL + lane * 4) = w;
        }
        // phase tables: lane half=0 -> cos pair, half=1 -> sin pair
        {
            const float bf = beta_p[0] * (1.0f / 64.0f);
            const int half = lane >> 5, i = lane & 31;
            float2 p = ((const float2*)(xr + 128))[i];
            float s0, c0, s1, c1;
            sincosf(p.x, &s0, &c0);
            sincosf(p.y, &s1, &c1);
            float v0 = half ? s0 : c0, v1 = half ? s1 : c1;
            unsigned ku = (unsigned)f2bf(v0)      | ((unsigned)f2bf(v1)      << 16);
            unsigned qu = (unsigned)f2bf(v0 * bf) | ((unsigned)f2bf(v1 * bf) << 16);
            const int soff = 24 + half * 64 + 2 * i;
            #pragma unroll
            for (int h = 0; h < 8; ++h)
                *(unsigned*)(QA + ((size_t)(b * 8 + h) * S_LEN + s) * KAUG + soff) = qu;
            #pragma unroll
            for (int kvh = 0; kvh < 4; ++kvh)
                *(unsigned*)(KA + ((size_t)(b * 4 + kvh) * S_LEN + s) * KAUG + soff) = ku;
        }
        // zero pads dims 152..159
        if (lane < 12) {
            uint4 z = {0u, 0u, 0u, 0u};
            unsigned short* base = (lane < 8)
                ? QA + ((size_t)(b * 8 + lane) * S_LEN + s) * KAUG
                : KA + ((size_t)(b * 4 + (lane - 8)) * S_LEN + s) * KAUG;
            *(uint4*)(base + 152) = z;
        }
    } else if (blk < 1038) {
        // W conversion: 27648 float4s total (Wq 9216 | Wkv 9216 | Wo 9216)
        const int t0 = (blk - 1024) * 256 + tid;
        #pragma unroll
        for (int it = 0; it < 8; ++it) {
            int idx = t0 + it * 3584;
            if (idx < 27648) {
                const float* src = (idx < 9216)  ? Wq  + (size_t)idx * 4
                                 : (idx < 18432) ? Wkv + (size_t)(idx - 9216) * 4
                                                 : Wo  + (size_t)(idx - 18432) * 4;
                float4 v = *(const float4*)src;
                uint2 w;
                w.x = (unsigned)f2bf(v.x) | ((unsigned)f2bf(v.y) << 16);
                w.y = (unsigned)f2bf(v.z) | ((unsigned)f2bf(v.w) << 16);
                *(uint2*)(Wb + (size_t)idx * 4) = w;
            }
        }
    } else {
        // VT pad rows d=24..31 for (b,kvh)=j
        const int j = blk - 1038;
        unsigned short* base = VT + ((size_t)j * 32 + 24) * S_LEN;
        uint4 z = {0u, 0u, 0u, 0u};
        #pragma unroll
        for (int c = 0; c < 8; ++c)
            *(uint4*)(base + (size_t)(c * 256 + tid) * 8) = z;
    }
}

// ============================================================
// K1: QKV GEMM — P = xb @ Wb[0:384]^T, epilogue scatters into
// QA (alpha*SCALE folded), KA, VT.  64x64 tile, K=192 staged once.
// ============================================================
__global__ __launch_bounds__(256) void qkv_gemm_kernel(
    const unsigned short* __restrict__ xb, const unsigned short* __restrict__ Wb,
    const float* __restrict__ alpha_p,
    unsigned short* __restrict__ QA, unsigned short* __restrict__ KA,
    unsigned short* __restrict__ VT)
{
    __shared__ __align__(16) unsigned short a_lds[64][200];
    __shared__ __align__(16) unsigned short b_lds[64][200];
    const int tid = threadIdx.x;
    const int wid = tid >> 6, lane = tid & 63, g = lane >> 4, lr = lane & 15;
    const int brow = blockIdx.x * 64;
    const int bcol = blockIdx.y * 64;

    #pragma unroll
    for (int c = 0; c < 6; ++c) {
        int idx = c * 256 + tid;
        int r = idx / 24, ch = idx % 24;
        *(uint4*)&a_lds[r][ch * 8] = *(const uint4*)&xb[(size_t)(brow + r) * 192 + ch * 8];
        *(uint4*)&b_lds[r][ch * 8] = *(const uint4*)&Wb[(size_t)(bcol + r) * 192 + ch * 8];
    }
    __syncthreads();

    f32x4 acc[4];
    #pragma unroll
    for (int nc = 0; nc < 4; ++nc) acc[nc] = (f32x4){0.f, 0.f, 0.f, 0.f};
    #pragma unroll
    for (int kc = 0; kc < 6; ++kc) {
        bf16x8 af = *(const bf16x8*)&a_lds[wid * 16 + lr][kc * 32 + g * 8];
        #pragma unroll
        for (int nc = 0; nc < 4; ++nc) {
            bf16x8 bfr = *(const bf16x8*)&b_lds[nc * 16 + lr][kc * 32 + g * 8];
            acc[nc] = __builtin_amdgcn_mfma_f32_16x16x32_bf16(af, bfr, acc[nc], 0, 0, 0);
        }
    }

    const float qs = alpha_p[0] * 0.20412414523193150818f; // alpha/sqrt(24)
    #pragma unroll
    for (int nc = 0; nc < 4; ++nc) {
        int c = bcol + nc * 16 + lr;
        #pragma unroll
        for (int r = 0; r < 4; ++r) {
            int row = brow + wid * 16 + g * 4 + r;
            int b = row >> 11, s = row & (S_LEN - 1);
            float v = acc[nc][r];
            if (c < 192) {
                int h = c / 24, d = c - 24 * h;
                QA[((size_t)(b * 8 + h) * S_LEN + s) * KAUG + d] = f2bf(v * qs);
            } else if (c < 288) {
                int cc = c - 192, kvh = cc / 24, d = cc - 24 * kvh;
                KA[((size_t)(b * 4 + kvh) * S_LEN + s) * KAUG + d] = f2bf(v);
            } else {
                int cc = c - 288, kvh = cc / 24, d = cc - 24 * kvh;
                VT[((size_t)(b * 4 + kvh) * 32 + d) * S_LEN + s] = f2bf(v);
            }
        }
    }
}

// ============================================================
// K2: fused flash attention (unchanged math; O now written bf16).
// mfma_f32_16x16x32_bf16 layouts (m89-verified):
//   A: lane l holds A[l&15][(l>>4)*8+j]   B: lane l holds B[(l>>4)*8+j][l&15]
//   D: lane l reg r holds D[(l>>4)*4+r][l&15]
// ============================================================
__global__ __launch_bounds__(256) void attn_kernel(
    const unsigned short* __restrict__ QA, const unsigned short* __restrict__ KA,
    const unsigned short* __restrict__ VT, unsigned short* __restrict__ Ob)
{
    __shared__ __align__(16) unsigned short ka_lds[32][168];
    __shared__ __align__(16) unsigned short vt_lds[32][40];
    __shared__ __align__(16) unsigned short pt_lds[4][32][20];

    const int tid = threadIdx.x;
    const int wid = tid >> 6, lane = tid & 63;
    const int g = lane >> 4, lr = lane & 15;

    const int bid = blockIdx.x;
    const int t = (S_LEN / 64 - 1) - (bid >> 4);
    const int bh = bid & 15;
    const int b = bh >> 3, h = bh & 7;
    const int kvh = h >> 1;
    const int qb = t * 64;
    const int q0w = qb + wid * 16;

    const unsigned short* qa_base = QA + (size_t)(b * 8 + h) * S_LEN * KAUG;
    const unsigned short* ka_base = KA + (size_t)(b * 4 + kvh) * S_LEN * KAUG;
    const unsigned short* vt_base = VT + (size_t)(b * 4 + kvh) * 32 * S_LEN;

    bf16x8 qfrag[5];
    #pragma unroll
    for (int kc = 0; kc < 5; ++kc) {
        const unsigned short* p = qa_base + (size_t)(q0w + lr) * KAUG + kc * 32 + g * 8;
        qfrag[kc] = *(const bf16x8*)p;
    }

    f32x4 acc0 = {0.f, 0.f, 0.f, 0.f};
    f32x4 acc1 = {0.f, 0.f, 0.f, 0.f};
    float mrow[4] = {-1e30f, -1e30f, -1e30f, -1e30f};
    float lrow[4] = {0.f, 0.f, 0.f, 0.f};
    const int wave_qmax = q0w + 15;
    const int ntiles = 2 * t + 2;

    for (int kt = 0; kt < ntiles; ++kt) {
        const int n0 = kt * 32;
        __syncthreads();
        {
            const unsigned* src = (const unsigned*)ka_base + (size_t)n0 * 80;
            unsigned* dst = (unsigned*)&ka_lds[0][0];
            #pragma unroll
            for (int c = 0; c < 10; ++c) {
                int idx = c * 256 + tid;
                int r = idx / 80, col = idx % 80;
                dst[r * 84 + col] = src[(size_t)r * 80 + col];
            }
            const unsigned* vsrc = (const unsigned*)vt_base + (n0 >> 1);
            unsigned* vdst = (unsigned*)&vt_lds[0][0];
            #pragma unroll
            for (int c = 0; c < 2; ++c) {
                int idx = c * 256 + tid;
                int r = idx / 16, col = idx % 16;
                vdst[r * 20 + col] = vsrc[(size_t)r * 1024 + col];
            }
        }
        __syncthreads();
        if (n0 > wave_qmax) continue;

        f32x4 sf[2] = {{0.f,0.f,0.f,0.f},{0.f,0.f,0.f,0.f}};
        #pragma unroll
        for (int nc = 0; nc < 2; ++nc) {
            #pragma unroll
            for (int kc = 0; kc < 5; ++kc) {
                bf16x8 bfr = *(const bf16x8*)&ka_lds[nc * 16 + lr][kc * 32 + g * 8];
                sf[nc] = __builtin_amdgcn_mfma_f32_16x16x32_bf16(qfrag[kc], bfr, sf[nc], 0, 0, 0);
            }
        }
        #pragma unroll
        for (int nc = 0; nc < 2; ++nc) {
            int n = n0 + nc * 16 + lr;
            #pragma unroll
            for (int r = 0; r < 4; ++r) {
                int q = q0w + g * 4 + r;
                if (n > q) sf[nc][r] = -1e30f;
            }
        }
        float tmax[4];
        #pragma unroll
        for (int r = 0; r < 4; ++r) tmax[r] = fmaxf(sf[0][r], sf[1][r]);
        #pragma unroll
        for (int off = 1; off < 16; off <<= 1) {
            #pragma unroll
            for (int r = 0; r < 4; ++r) tmax[r] = fmaxf(tmax[r], __shfl_xor(tmax[r], off, 64));
        }
        float corr[4];
        #pragma unroll
        for (int r = 0; r < 4; ++r) {
            float mnew = fmaxf(mrow[r], tmax[r]);
            corr[r] = __expf(mrow[r] - mnew);
            mrow[r] = mnew;
        }
        float p0[4], p1[4], tsum[4];
        #pragma unroll
        for (int r = 0; r < 4; ++r) {
            p0[r] = __expf(sf[0][r] - mrow[r]);
            p1[r] = __expf(sf[1][r] - mrow[r]);
            tsum[r] = p0[r] + p1[r];
        }
        #pragma unroll
        for (int off = 1; off < 16; off <<= 1) {
            #pragma unroll
            for (int r = 0; r < 4; ++r) tsum[r] += __shfl_xor(tsum[r], off, 64);
        }
        #pragma unroll
        for (int r = 0; r < 4; ++r) {
            lrow[r] = lrow[r] * corr[r] + tsum[r];
            acc0[r] *= corr[r];
            acc1[r] *= corr[r];
        }
        {
            ushort4 pk;
            pk.x = f2bf(p0[0]); pk.y = f2bf(p0[1]); pk.z = f2bf(p0[2]); pk.w = f2bf(p0[3]);
            *(ushort4*)&pt_lds[wid][lr][g * 4] = pk;
            pk.x = f2bf(p1[0]); pk.y = f2bf(p1[1]); pk.z = f2bf(p1[2]); pk.w = f2bf(p1[3]);
            *(ushort4*)&pt_lds[wid][16 + lr][g * 4] = pk;
        }
        bf16x8 afr;
        #pragma unroll
        for (int j = 0; j < 8; ++j) afr[j] = (short)pt_lds[wid][g * 8 + j][lr];
        {
            bf16x8 bfr0 = *(const bf16x8*)&vt_lds[lr][g * 8];
            acc0 = __builtin_amdgcn_mfma_f32_16x16x32_bf16(afr, bfr0, acc0, 0, 0, 0);
            bf16x8 bfr1 = *(const bf16x8*)&vt_lds[16 + lr][g * 8];
            acc1 = __builtin_amdgcn_mfma_f32_16x16x32_bf16(afr, bfr1, acc1, 0, 0, 0);
        }
    }

    float inv[4];
    #pragma unroll
    for (int r = 0; r < 4; ++r) inv[r] = 1.0f / lrow[r];
    {
        int d = lr;
        #pragma unroll
        for (int r = 0; r < 4; ++r) {
            int q = q0w + g * 4 + r;
            Ob[((size_t)b * S_LEN + q) * DMODEL + h * 24 + d] = f2bf(acc0[r] * inv[r]);
        }
        d = 16 + lr;
        if (d < 24) {
            #pragma unroll
            for (int r = 0; r < 4; ++r) {
                int q = q0w + g * 4 + r;
                Ob[((size_t)b * S_LEN + q) * DMODEL + h * 24 + d] = f2bf(acc1[r] * inv[r]);
            }
        }
    }
}

// ============================================================
// K3: out = Ob @ Wo^T  (bf16 MFMA, fp32 out)
// ============================================================
__global__ __launch_bounds__(256) void proj_gemm_kernel(
    const unsigned short* __restrict__ Ob, const unsigned short* __restrict__ Wob,
    float* __restrict__ out)
{
    __shared__ __align__(16) unsigned short a_lds[64][200];
    __shared__ __align__(16) unsigned short b_lds[64][200];
    const int tid = threadIdx.x;
    const int wid = tid >> 6, lane = tid & 63, g = lane >> 4, lr = lane & 15;
    const int brow = blockIdx.x * 64;
    const int bcol = blockIdx.y * 64;

    #pragma unroll
    for (int c = 0; c < 6; ++c) {
        int idx = c * 256 + tid;
        int r = idx / 24, ch = idx % 24;
        *(uint4*)&a_lds[r][ch * 8] = *(const uint4*)&Ob[(size_t)(brow + r) * 192 + ch * 8];
        *(uint4*)&b_lds[r][ch * 8] = *(const uint4*)&Wob[(size_t)(bcol + r) * 192 + ch * 8];
    }
    __syncthreads();

    f32x4 acc[4];
    #pragma unroll
    for (int nc = 0; nc < 4; ++nc) acc[nc] = (f32x4){0.f, 0.f, 0.f, 0.f};
    #pragma unroll
    for (int kc = 0; kc < 6; ++kc) {
        bf16x8 af = *(const bf16x8*)&a_lds[wid * 16 + lr][kc * 32 + g * 8];
        #pragma unroll
        for (int nc = 0; nc < 4; ++nc) {
            bf16x8 bfr = *(const bf16x8*)&b_lds[nc * 16 + lr][kc * 32 + g * 8];
            acc[nc] = __builtin_amdgcn_mfma_f32_16x16x32_bf16(af, bfr, acc[nc], 0, 0, 0);
        }
    }

    #pragma unroll
    for (int nc = 0; nc < 4; ++nc) {
        int c = bcol + nc * 16 + lr;
        #pragma unroll
        for (int r = 0; r < 4; ++r) {
            int row = brow + wid * 16 + g * 4 + r;
            out[(size_t)row * 192 + c] = acc[nc][r];
        }
    }
}

// ============================================================
extern "C" void kernel_launch(void* const* d_in, const int* in_sizes, int n_in,
                              void* d_out, int out_size, void* d_ws, size_t ws_size,
                              hipStream_t stream) {
    const float* x     = (const float*)d_in[0];
    const float* Wq    = (const float*)d_in[1];
    const float* Wkv   = (const float*)d_in[2];
    const float* Wo    = (const float*)d_in[3];
    const float* alpha = (const float*)d_in[4];
    const float* beta  = (const float*)d_in[5];

    char* ws = (char*)d_ws;
    const size_t QA_BYTES = (size_t)B_N * 8 * S_LEN * KAUG * 2;   // 10,485,760
    const size_t KA_BYTES = (size_t)B_N * 4 * S_LEN * KAUG * 2;   //  5,242,880
    const size_t VT_BYTES = (size_t)B_N * 4 * 32 * S_LEN * 2;     //  1,048,576
    const size_t XB_BYTES = (size_t)B_N * S_LEN * DMODEL * 2;     //  1,572,864
    const size_t WB_BYTES = (size_t)576 * 192 * 2;                //    221,184
    unsigned short* QA = (unsigned short*)ws;
    unsigned short* KA = (unsigned short*)(ws + QA_BYTES);
    unsigned short* VT = (unsigned short*)(ws + QA_BYTES + KA_BYTES);
    unsigned short* xb = (unsigned short*)(ws + QA_BYTES + KA_BYTES + VT_BYTES);
    unsigned short* Wb = (unsigned short*)(ws + QA_BYTES + KA_BYTES + VT_BYTES + XB_BYTES);
    unsigned short* Ob = (unsigned short*)(ws + QA_BYTES + KA_BYTES + VT_BYTES + XB_BYTES + WB_BYTES);
    float* out = (float*)d_out;

    hipLaunchKernelGGL(convert_kernel, dim3(1046), dim3(256), 0, stream,
                       x, Wq, Wkv, Wo, beta, xb, Wb, QA, KA, VT);
    hipLaunchKernelGGL(qkv_gemm_kernel, dim3(64, 6), dim3(256), 0, stream,
                       xb, Wb, alpha, QA, KA, VT);
    hipLaunchKernelGGL(attn_kernel, dim3(B_N * HQ_N * (S_LEN / 64)), dim3(256), 0, stream,
                       QA, KA, VT, Ob);
    hipLaunchKernelGGL(proj_gemm_kernel, dim3(64, 3), dim3(256), 0, stream,
                       Ob, Wb + (size_t)384 * 192, out);
}

// Round 3
// 92.572 us; speedup vs baseline: 3.2372x; 1.2958x over previous
//
#include <hip/hip_runtime.h>
#include <math.h>

// ---- problem constants ----
#define B_N    2
#define S_LEN  2048
#define DMODEL 192
#define HQ_N   8
#define HKV_N  4
#define DH_N   24
#define KAUG   160   // 24 q/k + 64 cos + 64 sin + 8 zero pad (= 5 * 32)
#define LOG2E  1.44269504088896340736f

typedef __attribute__((ext_vector_type(8))) short bf16x8;
typedef __attribute__((ext_vector_type(4))) float f32x4;

static __device__ __forceinline__ unsigned short f2bf(float f) {
    union { float f; unsigned u; } v; v.f = f;
    unsigned r = v.u + 0x7FFFu + ((v.u >> 16) & 1u);
    return (unsigned short)(r >> 16);
}

// ============================================================
// K0: convert — x->bf16, W->bf16, phase sincos -> QA/KA phase+pad
// sections, VT pad rows.  Q-side phase entries carry beta/64*log2e.
// ============================================================
__global__ __launch_bounds__(256) void convert_kernel(
    const float* __restrict__ x, const float* __restrict__ Wq,
    const float* __restrict__ Wkv, const float* __restrict__ Wo,
    const float* __restrict__ beta_p,
    unsigned short* __restrict__ xb, unsigned short* __restrict__ Wb,
    unsigned short* __restrict__ QA, unsigned short* __restrict__ KA,
    unsigned short* __restrict__ VT)
{
    const int blk = blockIdx.x, tid = threadIdx.x;
    if (blk < 1024) {
        const int wid = tid >> 6, lane = tid & 63;
        const int row = blk * 4 + wid;
        const int b = row >> 11, s = row & (S_LEN - 1);
        const float* xr = x + (size_t)row * DMODEL;
        if (lane < 48) {
            float4 v = ((const float4*)xr)[lane];
            uint2 w;
            w.x = (unsigned)f2bf(v.x) | ((unsigned)f2bf(v.y) << 16);
            w.y = (unsigned)f2bf(v.z) | ((unsigned)f2bf(v.w) << 16);
            *(uint2*)(xb + (size_t)row * DMODEL + lane * 4) = w;
        }
        {
            const float bf = beta_p[0] * (1.0f / 64.0f) * LOG2E;
            const int half = lane >> 5, i = lane & 31;
            float2 p = ((const float2*)(xr + 128))[i];
            float s0, c0, s1, c1;
            sincosf(p.x, &s0, &c0);
            sincosf(p.y, &s1, &c1);
            float v0 = half ? s0 : c0, v1 = half ? s1 : c1;
            unsigned ku = (unsigned)f2bf(v0)      | ((unsigned)f2bf(v1)      << 16);
            unsigned qu = (unsigned)f2bf(v0 * bf) | ((unsigned)f2bf(v1 * bf) << 16);
            const int soff = 24 + half * 64 + 2 * i;
            #pragma unroll
            for (int h = 0; h < 8; ++h)
                *(unsigned*)(QA + ((size_t)(b * 8 + h) * S_LEN + s) * KAUG + soff) = qu;
            #pragma unroll
            for (int kvh = 0; kvh < 4; ++kvh)
                *(unsigned*)(KA + ((size_t)(b * 4 + kvh) * S_LEN + s) * KAUG + soff) = ku;
        }
        if (lane < 12) {
            uint4 z = {0u, 0u, 0u, 0u};
            unsigned short* base = (lane < 8)
                ? QA + ((size_t)(b * 8 + lane) * S_LEN + s) * KAUG
                : KA + ((size_t)(b * 4 + (lane - 8)) * S_LEN + s) * KAUG;
            *(uint4*)(base + 152) = z;
        }
    } else if (blk < 1038) {
        const int t0 = (blk - 1024) * 256 + tid;
        #pragma unroll
        for (int it = 0; it < 8; ++it) {
            int idx = t0 + it * 3584;
            if (idx < 27648) {
                const float* src = (idx < 9216)  ? Wq  + (size_t)idx * 4
                                 : (idx < 18432) ? Wkv + (size_t)(idx - 9216) * 4
                                                 : Wo  + (size_t)(idx - 18432) * 4;
                float4 v = *(const float4*)src;
                uint2 w;
                w.x = (unsigned)f2bf(v.x) | ((unsigned)f2bf(v.y) << 16);
                w.y = (unsigned)f2bf(v.z) | ((unsigned)f2bf(v.w) << 16);
                *(uint2*)(Wb + (size_t)idx * 4) = w;
            }
        }
    } else {
        const int j = blk - 1038;
        unsigned short* base = VT + ((size_t)j * 32 + 24) * S_LEN;
        uint4 z = {0u, 0u, 0u, 0u};
        #pragma unroll
        for (int c = 0; c < 8; ++c)
            *(uint4*)(base + (size_t)(c * 256 + tid) * 8) = z;
    }
}

// ============================================================
// K1: QKV GEMM — epilogue scatters q (alpha*SCALE*log2e folded), k, v.
// ============================================================
__global__ __launch_bounds__(256) void qkv_gemm_kernel(
    const unsigned short* __restrict__ xb, const unsigned short* __restrict__ Wb,
    const float* __restrict__ alpha_p,
    unsigned short* __restrict__ QA, unsigned short* __restrict__ KA,
    unsigned short* __restrict__ VT)
{
    __shared__ __align__(16) unsigned short a_lds[64][200];
    __shared__ __align__(16) unsigned short b_lds[64][200];
    const int tid = threadIdx.x;
    const int wid = tid >> 6, lane = tid & 63, g = lane >> 4, lr = lane & 15;
    const int brow = blockIdx.x * 64;
    const int bcol = blockIdx.y * 64;

    #pragma unroll
    for (int c = 0; c < 6; ++c) {
        int idx = c * 256 + tid;
        int r = idx / 24, ch = idx % 24;
        *(uint4*)&a_lds[r][ch * 8] = *(const uint4*)&xb[(size_t)(brow + r) * 192 + ch * 8];
        *(uint4*)&b_lds[r][ch * 8] = *(const uint4*)&Wb[(size_t)(bcol + r) * 192 + ch * 8];
    }
    __syncthreads();

    f32x4 acc[4];
    #pragma unroll
    for (int nc = 0; nc < 4; ++nc) acc[nc] = (f32x4){0.f, 0.f, 0.f, 0.f};
    #pragma unroll
    for (int kc = 0; kc < 6; ++kc) {
        bf16x8 af = *(const bf16x8*)&a_lds[wid * 16 + lr][kc * 32 + g * 8];
        #pragma unroll
        for (int nc = 0; nc < 4; ++nc) {
            bf16x8 bfr = *(const bf16x8*)&b_lds[nc * 16 + lr][kc * 32 + g * 8];
            acc[nc] = __builtin_amdgcn_mfma_f32_16x16x32_bf16(af, bfr, acc[nc], 0, 0, 0);
        }
    }

    const float qs = alpha_p[0] * 0.20412414523193150818f * LOG2E;
    #pragma unroll
    for (int nc = 0; nc < 4; ++nc) {
        int c = bcol + nc * 16 + lr;
        #pragma unroll
        for (int r = 0; r < 4; ++r) {
            int row = brow + wid * 16 + g * 4 + r;
            int b = row >> 11, s = row & (S_LEN - 1);
            float v = acc[nc][r];
            if (c < 192) {
                int h = c / 24, d = c - 24 * h;
                QA[((size_t)(b * 8 + h) * S_LEN + s) * KAUG + d] = f2bf(v * qs);
            } else if (c < 288) {
                int cc = c - 192, kvh = cc / 24, d = cc - 24 * kvh;
                KA[((size_t)(b * 4 + kvh) * S_LEN + s) * KAUG + d] = f2bf(v);
            } else {
                int cc = c - 288, kvh = cc / 24, d = cc - 24 * kvh;
                VT[((size_t)(b * 4 + kvh) * 32 + d) * S_LEN + s] = f2bf(v);
            }
        }
    }
}

// ============================================================
// K2: fused flash attention, swapped-operand form.
// Per wave: 16 q rows (q = q0w + lane&15), KVBLK=64.
//  QK:  mfma(A=K, B=Q^T)  -> S[key 4g+r][q lr]   (per-lane q-local)
//  PV:  mfma(A=V^T, B=P^T)-> O[d 4g+r][q lr]
// P^T B-frag built via per-wave LDS bounce (2 b128 writes + 4 b64 reads).
// Scores are in log2 domain (log2e folded into QA scales); exp2 softmax.
// bid remap pairs t with 31-t on the same CU for load balance.
// ============================================================
__global__ __launch_bounds__(256) void attn_kernel(
    const unsigned short* __restrict__ QA, const unsigned short* __restrict__ KA,
    const unsigned short* __restrict__ VT, unsigned short* __restrict__ Ob)
{
    __shared__ __align__(16) unsigned short ka_lds[64][168]; // 64 keys x 160 dims (+pad)
    __shared__ __align__(16) unsigned short vt_lds[32][72];  // 32 d x 64 keys (+pad)
    __shared__ __align__(16) unsigned pw[4][64][8];          // per-wave P bounce

    const int tid = threadIdx.x;
    const int wid = tid >> 6, lane = tid & 63;
    const int g = lane >> 4, lr = lane & 15;

    const int bid = blockIdx.x;
    const int pair = bid & 255, which = bid >> 8;
    const int tIdx = pair >> 4;
    const int t = which ? tIdx : 31 - tIdx;     // co-resident pair sums to 31
    const int bh = pair & 15;
    const int b = bh >> 3, h = bh & 7;
    const int kvh = h >> 1;
    const int q0w = t * 64 + wid * 16;
    const int q = q0w + lr;

    const unsigned short* qa_base = QA + (size_t)(b * 8 + h) * S_LEN * KAUG;
    const unsigned short* ka_base = KA + (size_t)(b * 4 + kvh) * S_LEN * KAUG;
    const unsigned* vt_base = (const unsigned*)(VT + (size_t)(b * 4 + kvh) * 32 * S_LEN);

    // Q B-frag: lane holds Q[q=lr-row][dim g*8+j] per 32-dim chunk
    bf16x8 qfrag[5];
    #pragma unroll
    for (int kc = 0; kc < 5; ++kc)
        qfrag[kc] = *(const bf16x8*)(qa_base + (size_t)q * KAUG + kc * 32 + g * 8);

    // staging roles
    const int sr = tid >> 2, sq = tid & 3;   // KA: row sr(0..63), quad sq(0..3)
    const int vr = tid >> 3, vq = tid & 7;   // VT: row vr(0..31), quad vq(0..7)

    f32x4 acc0 = {0.f, 0.f, 0.f, 0.f};  // d = 4g+r
    f32x4 acc1 = {0.f, 0.f, 0.f, 0.f};  // d = 16+4g+r
    float mrow = -1e30f, lrow = 0.f;
    const int ntiles = t + 1;

    for (int kt = 0; kt < ntiles; ++kt) {
        const int n0 = kt * 64;
        __syncthreads();
        {
            const unsigned short* src = ka_base + (size_t)(n0 + sr) * KAUG + sq * 8;
            #pragma unroll
            for (int u = 0; u < 5; ++u)
                *(uint4*)&ka_lds[sr][sq * 8 + u * 32] = *(const uint4*)(src + u * 32);
            *(uint4*)&vt_lds[vr][vq * 8] =
                *(const uint4*)(vt_base + (size_t)vr * 1024 + (n0 >> 1) + vq * 4);
        }
        __syncthreads();

        // ---- scores: 4 key-subtiles (M=16) x 5 dim-chunks ----
        f32x4 sf[4];
        #pragma unroll
        for (int st = 0; st < 4; ++st) sf[st] = (f32x4){0.f, 0.f, 0.f, 0.f};
        #pragma unroll
        for (int kc = 0; kc < 5; ++kc) {
            #pragma unroll
            for (int st = 0; st < 4; ++st) {
                bf16x8 kf = *(const bf16x8*)&ka_lds[st * 16 + lr][kc * 32 + g * 8];
                sf[st] = __builtin_amdgcn_mfma_f32_16x16x32_bf16(kf, qfrag[kc], sf[st], 0, 0, 0);
            }
        }
        // ---- causal mask (diagonal tile only) ----
        if (kt == ntiles - 1) {
            #pragma unroll
            for (int st = 0; st < 4; ++st) {
                #pragma unroll
                for (int r = 0; r < 4; ++r) {
                    int key = n0 + st * 16 + 4 * g + r;
                    if (key > q) sf[st][r] = -1e30f;
                }
            }
        }
        // ---- online softmax, per-lane q-row ----
        float tmax = sf[0][0];
        #pragma unroll
        for (int st = 0; st < 4; ++st)
            #pragma unroll
            for (int r = 0; r < 4; ++r) tmax = fmaxf(tmax, sf[st][r]);
        tmax = fmaxf(tmax, __shfl_xor(tmax, 16, 64));
        tmax = fmaxf(tmax, __shfl_xor(tmax, 32, 64));
        float mnew = fmaxf(mrow, tmax);
        float corr = __builtin_amdgcn_exp2f(mrow - mnew);
        mrow = mnew;
        float p[4][4];
        float ts = 0.f;
        #pragma unroll
        for (int st = 0; st < 4; ++st)
            #pragma unroll
            for (int r = 0; r < 4; ++r) {
                p[st][r] = __builtin_amdgcn_exp2f(sf[st][r] - mrow);
                ts += p[st][r];
            }
        ts += __shfl_xor(ts, 16, 64);
        ts += __shfl_xor(ts, 32, 64);
        lrow = lrow * corr + ts;
        #pragma unroll
        for (int r = 0; r < 4; ++r) { acc0[r] *= corr; acc1[r] *= corr; }

        // ---- pack P -> bf16 pairs, bounce through per-wave LDS ----
        {
            uint4 w0, w1;
            w0.x = (unsigned)f2bf(p[0][0]) | ((unsigned)f2bf(p[0][1]) << 16);
            w0.y = (unsigned)f2bf(p[0][2]) | ((unsigned)f2bf(p[0][3]) << 16);
            w0.z = (unsigned)f2bf(p[1][0]) | ((unsigned)f2bf(p[1][1]) << 16);
            w0.w = (unsigned)f2bf(p[1][2]) | ((unsigned)f2bf(p[1][3]) << 16);
            w1.x = (unsigned)f2bf(p[2][0]) | ((unsigned)f2bf(p[2][1]) << 16);
            w1.y = (unsigned)f2bf(p[2][2]) | ((unsigned)f2bf(p[2][3]) << 16);
            w1.z = (unsigned)f2bf(p[3][0]) | ((unsigned)f2bf(p[3][1]) << 16);
            w1.w = (unsigned)f2bf(p[3][2]) | ((unsigned)f2bf(p[3][3]) << 16);
            *(uint4*)&pw[wid][lane][0] = w0;
            *(uint4*)&pw[wid][lane][4] = w1;
        }
        // ---- PV: 2 key-chunks of 32 ----
        const int s0 = (g & 1) * 32 + lr;
        const unsigned* row0 = pw[wid][s0];
        const unsigned* row1 = pw[wid][s0 + 16];
        const int doff = (g >> 1) * 2;
        #pragma unroll
        for (int c = 0; c < 2; ++c) {
            uint2 a01 = *(const uint2*)(row0 + c * 4 + doff);
            uint2 a23 = *(const uint2*)(row1 + c * 4 + doff);
            union { uint4 u; bf16x8 v; } pf;
            pf.u.x = a01.x; pf.u.y = a01.y; pf.u.z = a23.x; pf.u.w = a23.y;
            bf16x8 v0 = *(const bf16x8*)&vt_lds[lr][c * 32 + g * 8];
            bf16x8 v1 = *(const bf16x8*)&vt_lds[16 + lr][c * 32 + g * 8];
            acc0 = __builtin_amdgcn_mfma_f32_16x16x32_bf16(v0, pf.v, acc0, 0, 0, 0);
            acc1 = __builtin_amdgcn_mfma_f32_16x16x32_bf16(v1, pf.v, acc1, 0, 0, 0);
        }
    }

    // ---- finalize ----
    const float invl = 1.0f / lrow;
    unsigned short* ob = Ob + ((size_t)b * S_LEN + q) * DMODEL + h * 24;
    #pragma unroll
    for (int r = 0; r < 4; ++r)
        ob[4 * g + r] = f2bf(acc0[r] * invl);
    if (g < 2) {
        #pragma unroll
        for (int r = 0; r < 4; ++r)
            ob[16 + 4 * g + r] = f2bf(acc1[r] * invl);
    }
}

// ============================================================
// K3: out = Ob @ Wo^T  (bf16 MFMA, fp32 out)
// ============================================================
__global__ __launch_bounds__(256) void proj_gemm_kernel(
    const unsigned short* __restrict__ Ob, const unsigned short* __restrict__ Wob,
    float* __restrict__ out)
{
    __shared__ __align__(16) unsigned short a_lds[64][200];
    __shared__ __align__(16) unsigned short b_lds[64][200];
    const int tid = threadIdx.x;
    const int wid = tid >> 6, lane = tid & 63, g = lane >> 4, lr = lane & 15;
    const int brow = blockIdx.x * 64;
    const int bcol = blockIdx.y * 64;

    #pragma unroll
    for (int c = 0; c < 6; ++c) {
        int idx = c * 256 + tid;
        int r = idx / 24, ch = idx % 24;
        *(uint4*)&a_lds[r][ch * 8] = *(const uint4*)&Ob[(size_t)(brow + r) * 192 + ch * 8];
        *(uint4*)&b_lds[r][ch * 8] = *(const uint4*)&Wob[(size_t)(bcol + r) * 192 + ch * 8];
    }
    __syncthreads();

    f32x4 acc[4];
    #pragma unroll
    for (int nc = 0; nc < 4; ++nc) acc[nc] = (f32x4){0.f, 0.f, 0.f, 0.f};
    #pragma unroll
    for (int kc = 0; kc < 6; ++kc) {
        bf16x8 af = *(const bf16x8*)&a_lds[wid * 16 + lr][kc * 32 + g * 8];
        #pragma unroll
        for (int nc = 0; nc < 4; ++nc) {
            bf16x8 bfr = *(const bf16x8*)&b_lds[nc * 16 + lr][kc * 32 + g * 8];
            acc[nc] = __builtin_amdgcn_mfma_f32_16x16x32_bf16(af, bfr, acc[nc], 0, 0, 0);
        }
    }

    #pragma unroll
    for (int nc = 0; nc < 4; ++nc) {
        int c = bcol + nc * 16 + lr;
        #pragma unroll
        for (int r = 0; r < 4; ++r) {
            int row = brow + wid * 16 + g * 4 + r;
            out[(size_t)row * 192 + c] = acc[nc][r];
        }
    }
}

// ============================================================
extern "C" void kernel_launch(void* const* d_in, const int* in_sizes, int n_in,
                              void* d_out, int out_size, void* d_ws, size_t ws_size,
                              hipStream_t stream) {
    const float* x     = (const float*)d_in[0];
    const float* Wq    = (const float*)d_in[1];
    const float* Wkv   = (const float*)d_in[2];
    const float* Wo    = (const float*)d_in[3];
    const float* alpha = (const float*)d_in[4];
    const float* beta  = (const float*)d_in[5];

    char* ws = (char*)d_ws;
    const size_t QA_BYTES = (size_t)B_N * 8 * S_LEN * KAUG * 2;
    const size_t KA_BYTES = (size_t)B_N * 4 * S_LEN * KAUG * 2;
    const size_t VT_BYTES = (size_t)B_N * 4 * 32 * S_LEN * 2;
    const size_t XB_BYTES = (size_t)B_N * S_LEN * DMODEL * 2;
    const size_t WB_BYTES = (size_t)576 * 192 * 2;
    unsigned short* QA = (unsigned short*)ws;
    unsigned short* KA = (unsigned short*)(ws + QA_BYTES);
    unsigned short* VT = (unsigned short*)(ws + QA_BYTES + KA_BYTES);
    unsigned short* xb = (unsigned short*)(ws + QA_BYTES + KA_BYTES + VT_BYTES);
    unsigned short* Wb = (unsigned short*)(ws + QA_BYTES + KA_BYTES + VT_BYTES + XB_BYTES);
    unsigned short* Ob = (unsigned short*)(ws + QA_BYTES + KA_BYTES + VT_BYTES + XB_BYTES + WB_BYTES);
    float* out = (float*)d_out;

    hipLaunchKernelGGL(convert_kernel, dim3(1046), dim3(256), 0, stream,
                       x, Wq, Wkv, Wo, beta, xb, Wb, QA, KA, VT);
    hipLaunchKernelGGL(qkv_gemm_kernel, dim3(64, 6), dim3(256), 0, stream,
                       xb, Wb, alpha, QA, KA, VT);
    hipLaunchKernelGGL(attn_kernel, dim3(B_N * HQ_N * (S_LEN / 64)), dim3(256), 0, stream,
                       QA, KA, VT, Ob);
    hipLaunchKernelGGL(proj_gemm_kernel, dim3(64, 3), dim3(256), 0, stream,
                       Ob, Wb + (size_t)384 * 192, out);
}

// Round 4
// 75.738 us; speedup vs baseline: 3.9567x; 1.2223x over previous
//
#include <hip/hip_runtime.h>
#include <math.h>

// ---- problem constants ----
#define B_N    2
#define S_LEN  2048
#define DMODEL 192
#define HQ_N   8
#define HKV_N  4
#define DH_N   24
#define KAUG   160   // 24 q/k + 64 cos + 64 sin + 8 zero pad (= 10 * 16)
#define LOG2E  1.44269504088896340736f

typedef __attribute__((ext_vector_type(8)))  short bf16x8;
typedef __attribute__((ext_vector_type(4)))  float f32x4;
typedef __attribute__((ext_vector_type(16))) float f32x16;

static __device__ __forceinline__ unsigned short f2bf(float f) {
    union { float f; unsigned u; } v; v.f = f;
    unsigned r = v.u + 0x7FFFu + ((v.u >> 16) & 1u);
    return (unsigned short)(r >> 16);
}

static __device__ __forceinline__ unsigned cvtpk_bf16(float a, float b) {
    unsigned r;
    asm("v_cvt_pk_bf16_f32 %0, %1, %2" : "=v"(r) : "v"(a), "v"(b));
    return r;
}

typedef __attribute__((address_space(3))) unsigned short lds_us;
typedef const __attribute__((address_space(1))) unsigned short glb_us;
static __device__ __forceinline__ void gld16(const unsigned short* g, unsigned short* l) {
    __builtin_amdgcn_global_load_lds((glb_us*)g, (lds_us*)l, 16, 0, 0);
}

// ============================================================
// K0: convert — x->bf16, W->bf16, phase sincos -> QA/KA phase+pad
// sections, VT pad rows.  Q-side phase entries carry beta/64*log2e.
// ============================================================
__global__ __launch_bounds__(256) void convert_kernel(
    const float* __restrict__ x, const float* __restrict__ Wq,
    const float* __restrict__ Wkv, const float* __restrict__ Wo,
    const float* __restrict__ beta_p,
    unsigned short* __restrict__ xb, unsigned short* __restrict__ Wb,
    unsigned short* __restrict__ QA, unsigned short* __restrict__ KA,
    unsigned short* __restrict__ VT)
{
    const int blk = blockIdx.x, tid = threadIdx.x;
    if (blk < 1024) {
        const int wid = tid >> 6, lane = tid & 63;
        const int row = blk * 4 + wid;
        const int b = row >> 11, s = row & (S_LEN - 1);
        const float* xr = x + (size_t)row * DMODEL;
        if (lane < 48) {
            float4 v = ((const float4*)xr)[lane];
            uint2 w;
            w.x = (unsigned)f2bf(v.x) | ((unsigned)f2bf(v.y) << 16);
            w.y = (unsigned)f2bf(v.z) | ((unsigned)f2bf(v.w) << 16);
            *(uint2*)(xb + (size_t)row * DMODEL + lane * 4) = w;
        }
        {
            const float bf = beta_p[0] * (1.0f / 64.0f) * LOG2E;
            const int half = lane >> 5, i = lane & 31;
            float2 p = ((const float2*)(xr + 128))[i];
            float s0, c0, s1, c1;
            sincosf(p.x, &s0, &c0);
            sincosf(p.y, &s1, &c1);
            float v0 = half ? s0 : c0, v1 = half ? s1 : c1;
            unsigned ku = (unsigned)f2bf(v0)      | ((unsigned)f2bf(v1)      << 16);
            unsigned qu = (unsigned)f2bf(v0 * bf) | ((unsigned)f2bf(v1 * bf) << 16);
            const int soff = 24 + half * 64 + 2 * i;
            #pragma unroll
            for (int h = 0; h < 8; ++h)
                *(unsigned*)(QA + ((size_t)(b * 8 + h) * S_LEN + s) * KAUG + soff) = qu;
            #pragma unroll
            for (int kvh = 0; kvh < 4; ++kvh)
                *(unsigned*)(KA + ((size_t)(b * 4 + kvh) * S_LEN + s) * KAUG + soff) = ku;
        }
        if (lane < 12) {
            uint4 z = {0u, 0u, 0u, 0u};
            unsigned short* base = (lane < 8)
                ? QA + ((size_t)(b * 8 + lane) * S_LEN + s) * KAUG
                : KA + ((size_t)(b * 4 + (lane - 8)) * S_LEN + s) * KAUG;
            *(uint4*)(base + 152) = z;
        }
    } else if (blk < 1038) {
        const int t0 = (blk - 1024) * 256 + tid;
        #pragma unroll
        for (int it = 0; it < 8; ++it) {
            int idx = t0 + it * 3584;
            if (idx < 27648) {
                const float* src = (idx < 9216)  ? Wq  + (size_t)idx * 4
                                 : (idx < 18432) ? Wkv + (size_t)(idx - 9216) * 4
                                                 : Wo  + (size_t)(idx - 18432) * 4;
                float4 v = *(const float4*)src;
                uint2 w;
                w.x = (unsigned)f2bf(v.x) | ((unsigned)f2bf(v.y) << 16);
                w.y = (unsigned)f2bf(v.z) | ((unsigned)f2bf(v.w) << 16);
                *(uint2*)(Wb + (size_t)idx * 4) = w;
            }
        }
    } else {
        const int j = blk - 1038;
        unsigned short* base = VT + ((size_t)j * 32 + 24) * S_LEN;
        uint4 z = {0u, 0u, 0u, 0u};
        #pragma unroll
        for (int c = 0; c < 8; ++c)
            *(uint4*)(base + (size_t)(c * 256 + tid) * 8) = z;
    }
}

// ============================================================
// K1: QKV GEMM — epilogue scatters q (alpha*SCALE*log2e folded), k, v.
// ============================================================
__global__ __launch_bounds__(256) void qkv_gemm_kernel(
    const unsigned short* __restrict__ xb, const unsigned short* __restrict__ Wb,
    const float* __restrict__ alpha_p,
    unsigned short* __restrict__ QA, unsigned short* __restrict__ KA,
    unsigned short* __restrict__ VT)
{
    __shared__ __align__(16) unsigned short a_lds[64][200];
    __shared__ __align__(16) unsigned short b_lds[64][200];
    const int tid = threadIdx.x;
    const int wid = tid >> 6, lane = tid & 63, g = lane >> 4, lr = lane & 15;
    const int brow = blockIdx.x * 64;
    const int bcol = blockIdx.y * 64;

    #pragma unroll
    for (int c = 0; c < 6; ++c) {
        int idx = c * 256 + tid;
        int r = idx / 24, ch = idx % 24;
        *(uint4*)&a_lds[r][ch * 8] = *(const uint4*)&xb[(size_t)(brow + r) * 192 + ch * 8];
        *(uint4*)&b_lds[r][ch * 8] = *(const uint4*)&Wb[(size_t)(bcol + r) * 192 + ch * 8];
    }
    __syncthreads();

    f32x4 acc[4];
    #pragma unroll
    for (int nc = 0; nc < 4; ++nc) acc[nc] = (f32x4){0.f, 0.f, 0.f, 0.f};
    #pragma unroll
    for (int kc = 0; kc < 6; ++kc) {
        bf16x8 af = *(const bf16x8*)&a_lds[wid * 16 + lr][kc * 32 + g * 8];
        #pragma unroll
        for (int nc = 0; nc < 4; ++nc) {
            bf16x8 bfr = *(const bf16x8*)&b_lds[nc * 16 + lr][kc * 32 + g * 8];
            acc[nc] = __builtin_amdgcn_mfma_f32_16x16x32_bf16(af, bfr, acc[nc], 0, 0, 0);
        }
    }

    const float qs = alpha_p[0] * 0.20412414523193150818f * LOG2E;
    #pragma unroll
    for (int nc = 0; nc < 4; ++nc) {
        int c = bcol + nc * 16 + lr;
        #pragma unroll
        for (int r = 0; r < 4; ++r) {
            int row = brow + wid * 16 + g * 4 + r;
            int b = row >> 11, s = row & (S_LEN - 1);
            float v = acc[nc][r];
            if (c < 192) {
                int h = c / 24, d = c - 24 * h;
                QA[((size_t)(b * 8 + h) * S_LEN + s) * KAUG + d] = f2bf(v * qs);
            } else if (c < 288) {
                int cc = c - 192, kvh = cc / 24, d = cc - 24 * kvh;
                KA[((size_t)(b * 4 + kvh) * S_LEN + s) * KAUG + d] = f2bf(v);
            } else {
                int cc = c - 288, kvh = cc / 24, d = cc - 24 * kvh;
                VT[((size_t)(b * 4 + kvh) * 32 + d) * S_LEN + s] = f2bf(v);
            }
        }
    }
}

// ============================================================
// K2: fused flash attention — 32x32 MFMA, swapped operands.
// Block = 4 waves; waves 0,1 -> q-tile tA=31-pb, waves 2,3 -> tB=pb
// (folded for balanced wall time).  Wave = 32 q rows (q-col = lane&31).
// KVBLK=64; KA/VT staged via global_load_lds, double-buffered,
// counted vmcnt(6), raw s_barrier.  KA LDS XOR-swizzled via
// pre-swizzled global source (granule ^ (row&7); 2-bit tail swizzle).
// QK:  mfma_32x32x16(A=K, B=Q^T) -> S[key][q]
// Softmax in-register (per-lane column), log2-domain, exp2.
// P -> PV B-frags via 16 cvt_pk + 8 v_permlane32_swap_b32 (no LDS).
// PV:  mfma(A=V^T, B=P^T) -> O[d][q].
// ============================================================
__global__ __launch_bounds__(256) void attn_kernel(
    const unsigned short* __restrict__ QA, const unsigned short* __restrict__ KA,
    const unsigned short* __restrict__ VT, unsigned short* __restrict__ Ob)
{
    __shared__ __align__(16) unsigned short ka_lds[2][64 * KAUG]; // 2 x 20 KiB
    __shared__ __align__(16) unsigned short vt_lds[2][32 * 64];   // 2 x 4 KiB

    const int tid = threadIdx.x;
    const int wid = tid >> 6, lane = tid & 63;
    const int hi = lane >> 5, c31 = lane & 31;
    const int rs = c31 & 7, w2 = (c31 >> 1) & 3;

    const int bid = blockIdx.x;
    const int bh = bid >> 4, pb = bid & 15;
    const int b = bh >> 3, h = bh & 7, kvh = h >> 1;
    const int tA = 31 - pb;               // big tile (waves 0,1)
    const int tB = pb;                    // small tile (waves 2,3)
    const int myT = (wid < 2) ? tA : tB;
    const int q0w = myT * 64 + (wid & 1) * 32;
    const int q = q0w + c31;
    const int ntiles = tA + 1;            // staged kv tiles (= 32 - pb)

    const unsigned short* ka_g = KA + (size_t)(b * 4 + kvh) * S_LEN * KAUG;
    const unsigned short* vt_g = VT + (size_t)(b * 4 + kvh) * 32 * S_LEN;

    // ---- Q fragments: 10 x b128 (dims 16kc + 8hi + 0..7), stay in regs ----
    bf16x8 qf[10];
    {
        const unsigned short* qa = QA + ((size_t)(b * 8 + h) * S_LEN + q) * KAUG + hi * 8;
        #pragma unroll
        for (int kc = 0; kc < 10; ++kc) qf[kc] = *(const bf16x8*)(qa + kc * 16);
    }

    // ---- staging address precompute (per-lane, tile-invariant) ----
    int ka_soff[5], ka_doff[5], vt_soff, vt_doff;
    #pragma unroll
    for (int u = 0; u < 5; ++u) {
        int si = (wid * 5 + u) * 512 + lane * 8;     // dest short index (linear)
        int row = si / 160;
        int colg = (si - row * 160) >> 3;            // 0..19
        int g2 = (colg < 16) ? (colg ^ (row & 7))
                             : (16 + ((colg & 3) ^ ((row >> 1) & 3)));
        ka_soff[u] = row * KAUG + g2 * 8;            // + n0*KAUG at stage time
        ka_doff[u] = si;
    }
    {
        int si = wid * 512 + lane * 8;
        int row = si >> 6, colg = (si & 63) >> 3;
        vt_soff = row * S_LEN + (colg ^ (row & 7)) * 8;   // + n0 at stage time
        vt_doff = si;
    }

    // ---- ds_read offsets (shorts), tile-invariant ----
    unsigned offA[10], offV[4];
    #pragma unroll
    for (int kc = 0; kc < 10; ++kc) {
        int g = 2 * kc + hi;
        int pg = (kc < 8) ? (g ^ rs) : (16 + ((g & 3) ^ w2));
        offA[kc] = c31 * KAUG + pg * 8;
    }
    #pragma unroll
    for (int ks = 0; ks < 4; ++ks)
        offV[ks] = c31 * 64 + ((2 * ks + hi) ^ rs) * 8;

    auto STAGE = [&](int bufsel, int kt_) {
        const int n0 = kt_ * 64;
        const unsigned short* kg = ka_g + (size_t)n0 * KAUG;
        #pragma unroll
        for (int u = 0; u < 5; ++u)
            gld16(kg + ka_soff[u], &ka_lds[bufsel][ka_doff[u]]);
        gld16(vt_g + n0 + vt_soff, &vt_lds[bufsel][vt_doff]);
    };

    f32x16 acc = {0,0,0,0,0,0,0,0,0,0,0,0,0,0,0,0};
    float m = -1e30f, l = 0.f;

    STAGE(0, 0);
    STAGE(1, 1);

    for (int kt = 0; kt < ntiles; ++kt) {
        const int buf = kt & 1;
        if (kt + 1 < ntiles) asm volatile("s_waitcnt vmcnt(6)" ::: "memory");
        else                 asm volatile("s_waitcnt vmcnt(0)" ::: "memory");
        __builtin_amdgcn_s_barrier();

        if (kt <= myT) {
            const unsigned short* kb = &ka_lds[buf][0];
            const unsigned short* vb = &vt_lds[buf][0];
            f32x16 s0 = {0,0,0,0,0,0,0,0,0,0,0,0,0,0,0,0};
            f32x16 s1 = {0,0,0,0,0,0,0,0,0,0,0,0,0,0,0,0};
            #pragma unroll
            for (int kc = 0; kc < 10; ++kc) {
                bf16x8 a0 = *(const bf16x8*)(kb + offA[kc]);
                bf16x8 a1 = *(const bf16x8*)(kb + offA[kc] + 32 * KAUG);
                s0 = __builtin_amdgcn_mfma_f32_32x32x16_bf16(a0, qf[kc], s0, 0, 0, 0);
                s1 = __builtin_amdgcn_mfma_f32_32x32x16_bf16(a1, qf[kc], s1, 0, 0, 0);
            }
            // causal mask, diagonal tile only
            if (kt == myT) {
                const int qc = (wid & 1) * 32 + c31;
                #pragma unroll
                for (int r = 0; r < 16; ++r) {
                    int krow = (r & 3) + 8 * (r >> 2) + 4 * hi;
                    if (krow > qc)      s0[r] = -1e30f;
                    if (krow + 32 > qc) s1[r] = -1e30f;
                }
            }
            // ---- online softmax (per-lane q-column; cross-half via shfl 32) ----
            float tmax = s0[0];
            #pragma unroll
            for (int r = 1; r < 16; ++r) tmax = fmaxf(tmax, s0[r]);
            #pragma unroll
            for (int r = 0; r < 16; ++r) tmax = fmaxf(tmax, s1[r]);
            tmax = fmaxf(tmax, __shfl_xor(tmax, 32, 64));
            float mnew = fmaxf(m, tmax);
            float corr = __builtin_amdgcn_exp2f(m - mnew);
            m = mnew;
            float ts = 0.f;
            #pragma unroll
            for (int r = 0; r < 16; ++r) {
                s0[r] = __builtin_amdgcn_exp2f(s0[r] - m);
                s1[r] = __builtin_amdgcn_exp2f(s1[r] - m);
                ts += s0[r] + s1[r];
            }
            ts += __shfl_xor(ts, 32, 64);
            l = l * corr + ts;
            #pragma unroll
            for (int r = 0; r < 16; ++r) acc[r] *= corr;

            // ---- pack P (bf16 pairs) ----
            unsigned W0[8], W1[8];
            #pragma unroll
            for (int j = 0; j < 8; ++j) {
                W0[j] = cvtpk_bf16(s0[2 * j], s0[2 * j + 1]);
                W1[j] = cvtpk_bf16(s1[2 * j], s1[2 * j + 1]);
            }
            // ---- PV: B-frag via permlane32_swap, A = V^T from LDS ----
            union U16 { unsigned d[4]; bf16x8 v; };
#define PVSTEP(Warr, e, ks) { \
            unsigned x  = Warr[4 * e],     y  = Warr[4 * e + 2]; \
            unsigned x2 = Warr[4 * e + 1], y2 = Warr[4 * e + 3]; \
            asm volatile("v_permlane32_swap_b32 %0, %1" : "+v"(x),  "+v"(y)); \
            asm volatile("v_permlane32_swap_b32 %0, %1" : "+v"(x2), "+v"(y2)); \
            U16 pf; pf.d[0] = x; pf.d[1] = x2; pf.d[2] = y; pf.d[3] = y2; \
            bf16x8 av = *(const bf16x8*)(vb + offV[ks]); \
            acc = __builtin_amdgcn_mfma_f32_32x32x16_bf16(av, pf.v, acc, 0, 0, 0); }
            PVSTEP(W0, 0, 0)
            PVSTEP(W0, 1, 1)
            PVSTEP(W1, 0, 2)
            PVSTEP(W1, 1, 3)
#undef PVSTEP
        }

        __builtin_amdgcn_s_barrier();
        if (kt + 2 < ntiles) STAGE(buf, kt + 2);
    }

    // ---- finalize: O[b][q][h*24+d], d = (reg&3)+8*(reg>>2)+4*hi (regs 0..11) ----
    const float invl = 1.0f / l;
    unsigned short* ob = Ob + ((size_t)b * S_LEN + q) * DMODEL + h * 24 + 4 * hi;
    #pragma unroll
    for (int k = 0; k < 3; ++k) {
        unsigned u0 = (unsigned)f2bf(acc[4 * k] * invl) |
                      ((unsigned)f2bf(acc[4 * k + 1] * invl) << 16);
        unsigned u1 = (unsigned)f2bf(acc[4 * k + 2] * invl) |
                      ((unsigned)f2bf(acc[4 * k + 3] * invl) << 16);
        *(unsigned*)(ob + 8 * k)     = u0;
        *(unsigned*)(ob + 8 * k + 2) = u1;
    }
}

// ============================================================
// K3: out = Ob @ Wo^T  (bf16 MFMA, fp32 out)
// ============================================================
__global__ __launch_bounds__(256) void proj_gemm_kernel(
    const unsigned short* __restrict__ Ob, const unsigned short* __restrict__ Wob,
    float* __restrict__ out)
{
    __shared__ __align__(16) unsigned short a_lds[64][200];
    __shared__ __align__(16) unsigned short b_lds[64][200];
    const int tid = threadIdx.x;
    const int wid = tid >> 6, lane = tid & 63, g = lane >> 4, lr = lane & 15;
    const int brow = blockIdx.x * 64;
    const int bcol = blockIdx.y * 64;

    #pragma unroll
    for (int c = 0; c < 6; ++c) {
        int idx = c * 256 + tid;
        int r = idx / 24, ch = idx % 24;
        *(uint4*)&a_lds[r][ch * 8] = *(const uint4*)&Ob[(size_t)(brow + r) * 192 + ch * 8];
        *(uint4*)&b_lds[r][ch * 8] = *(const uint4*)&Wob[(size_t)(bcol + r) * 192 + ch * 8];
    }
    __syncthreads();

    f32x4 acc[4];
    #pragma unroll
    for (int nc = 0; nc < 4; ++nc) acc[nc] = (f32x4){0.f, 0.f, 0.f, 0.f};
    #pragma unroll
    for (int kc = 0; kc < 6; ++kc) {
        bf16x8 af = *(const bf16x8*)&a_lds[wid * 16 + lr][kc * 32 + g * 8];
        #pragma unroll
        for (int nc = 0; nc < 4; ++nc) {
            bf16x8 bfr = *(const bf16x8*)&b_lds[nc * 16 + lr][kc * 32 + g * 8];
            acc[nc] = __builtin_amdgcn_mfma_f32_16x16x32_bf16(af, bfr, acc[nc], 0, 0, 0);
        }
    }

    #pragma unroll
    for (int nc = 0; nc < 4; ++nc) {
        int c = bcol + nc * 16 + lr;
        #pragma unroll
        for (int r = 0; r < 4; ++r) {
            int row = brow + wid * 16 + g * 4 + r;
            out[(size_t)row * 192 + c] = acc[nc][r];
        }
    }
}

// ============================================================
extern "C" void kernel_launch(void* const* d_in, const int* in_sizes, int n_in,
                              void* d_out, int out_size, void* d_ws, size_t ws_size,
                              hipStream_t stream) {
    const float* x     = (const float*)d_in[0];
    const float* Wq    = (const float*)d_in[1];
    const float* Wkv   = (const float*)d_in[2];
    const float* Wo    = (const float*)d_in[3];
    const float* alpha = (const float*)d_in[4];
    const float* beta  = (const float*)d_in[5];

    char* ws = (char*)d_ws;
    const size_t QA_BYTES = (size_t)B_N * 8 * S_LEN * KAUG * 2;
    const size_t KA_BYTES = (size_t)B_N * 4 * S_LEN * KAUG * 2;
    const size_t VT_BYTES = (size_t)B_N * 4 * 32 * S_LEN * 2;
    const size_t XB_BYTES = (size_t)B_N * S_LEN * DMODEL * 2;
    const size_t WB_BYTES = (size_t)576 * 192 * 2;
    unsigned short* QA = (unsigned short*)ws;
    unsigned short* KA = (unsigned short*)(ws + QA_BYTES);
    unsigned short* VT = (unsigned short*)(ws + QA_BYTES + KA_BYTES);
    unsigned short* xb = (unsigned short*)(ws + QA_BYTES + KA_BYTES + VT_BYTES);
    unsigned short* Wb = (unsigned short*)(ws + QA_BYTES + KA_BYTES + VT_BYTES + XB_BYTES);
    unsigned short* Ob = (unsigned short*)(ws + QA_BYTES + KA_BYTES + VT_BYTES + XB_BYTES + WB_BYTES);
    float* out = (float*)d_out;

    hipLaunchKernelGGL(convert_kernel, dim3(1046), dim3(256), 0, stream,
                       x, Wq, Wkv, Wo, beta, xb, Wb, QA, KA, VT);
    hipLaunchKernelGGL(qkv_gemm_kernel, dim3(64, 6), dim3(256), 0, stream,
                       xb, Wb, alpha, QA, KA, VT);
    hipLaunchKernelGGL(attn_kernel, dim3(256), dim3(256), 0, stream,
                       QA, KA, VT, Ob);
    hipLaunchKernelGGL(proj_gemm_kernel, dim3(64, 3), dim3(256), 0, stream,
                       Ob, Wb + (size_t)384 * 192, out);
}